// Round 14
// baseline (84.940 us; speedup 1.0000x reference)
//
#include <hip/hip_runtime.h>
#include <hip/hip_bf16.h>

typedef __bf16 bf16;
typedef __bf16 bf16x4 __attribute__((ext_vector_type(4)));
typedef __bf16 bf16x8 __attribute__((ext_vector_type(8)));
typedef float f32x4 __attribute__((ext_vector_type(4)));

#define D 256          // embed dim
#define NHEAD 8
#define HD 32          // head dim
#define NB_ 8
#define LQ_ 256
#define LS_ 4096
#define MQ (NB_ * LQ_)   // 2048
#define MS (NB_ * LS_)   // 32768

// softmax scale folded into Q projection: hd^-0.5 * log2(e)
#define QSCALE 0.25500527f

// ---------------------------------------------------------------------------
// prep: SPb = bf16(source+pe); QPb = bf16(query+qpe); Wb = bf16(weights).
// [r10-proven; deleting it regresses gemm 18 -> 95 us (r11): L3-warm matters]
// ---------------------------------------------------------------------------
__global__ __launch_bounds__(256) void prep(
    const float* __restrict__ source, const float* __restrict__ source_pe,
    const float* __restrict__ query, const float* __restrict__ query_pe,
    const float* __restrict__ w_in, const float* __restrict__ w_out,
    bf16* __restrict__ SPb, bf16* __restrict__ QPb, bf16* __restrict__ Wb)
{
    const int NS4 = MS * D / 4;                  // 2097152
    const int NQ4 = MQ * D / 4;                  // 131072
    const int NW4 = (768 * 256 + 256 * 256) / 4; // 65536
    const int total = NS4 + NQ4 + NW4;
    for (int i = blockIdx.x * 256 + threadIdx.x; i < total; i += gridDim.x * 256) {
        if (i < NS4) {
            const float4 s = ((const float4*)source)[i];
            const float4 p = ((const float4*)source_pe)[i];
            bf16x4 osp;
            osp[0] = (bf16)(s.x + p.x); osp[1] = (bf16)(s.y + p.y);
            osp[2] = (bf16)(s.z + p.z); osp[3] = (bf16)(s.w + p.w);
            ((bf16x4*)SPb)[i] = osp;
        } else if (i < NS4 + NQ4) {
            const int j = i - NS4;
            const float4 s = ((const float4*)query)[j];
            const float4 p = ((const float4*)query_pe)[j];
            bf16x4 o;
            o[0] = (bf16)(s.x + p.x); o[1] = (bf16)(s.y + p.y);
            o[2] = (bf16)(s.z + p.z); o[3] = (bf16)(s.w + p.w);
            ((bf16x4*)QPb)[j] = o;
        } else {
            const int j = i - NS4 - NQ4;
            const float4 v = (j < 49152) ? ((const float4*)w_in)[j]
                                         : ((const float4*)w_out)[j - 49152];
            bf16x4 o;
            o[0] = (bf16)v.x; o[1] = (bf16)v.y; o[2] = (bf16)v.z; o[3] = (bf16)v.w;
            ((bf16x4*)Wb)[j] = o;
        }
    }
}

// ---------------------------------------------------------------------------
// projection GEMM, 128x128 tiles, ONE dispatch (grid 1056):  [r10-proven]
//   id<512   : K from SPb (bf16 staging)   -> Kt via LDS restage
//   id<1024  : V from f32 source (L3-warm) -> Vt2 direct (coalesced 8B)
//   id<1056  : Q from QPb                  -> Qb row-major, scaled
// ---------------------------------------------------------------------------
__global__ __launch_bounds__(256, 4) void gemm_proj(
    const bf16* __restrict__ SPb, const float* __restrict__ srcf,
    const bf16* __restrict__ QPb, const bf16* __restrict__ Wb,
    const float* __restrict__ in_proj_b,
    bf16* __restrict__ Kt, bf16* __restrict__ Vt2, bf16* __restrict__ Qb)
{
    __shared__ __align__(16) bf16 smem[2][128][72];   // As ++ Bs (36KB)
    bf16 (*As)[72] = smem[0];
    bf16 (*Bs)[72] = smem[1];
    const int tid = threadIdx.x, lane = tid & 63, wid = tid >> 6;
    const int wm = wid >> 1, wn = wid & 1;
    const int g = lane >> 4, q15 = lane & 15;
    const int id = blockIdx.x;

    const bf16* A; const bf16* W; const float* bias; bf16* out;
    int omode, mblk, nblk;        // omode: 0=Q row-major, 1=Kt, 2=Vt2
    if (id < 512) {
        A = SPb; W = Wb + 256 * D; bias = in_proj_b + 256; out = Kt;
        mblk = id >> 1; nblk = id & 1; omode = 1;
    } else if (id < 1024) {
        A = nullptr; W = Wb + 512 * D; bias = in_proj_b + 512; out = Vt2;
        mblk = (id - 512) >> 1; nblk = id & 1; omode = 2;
    } else {
        A = QPb; W = Wb; bias = in_proj_b; out = Qb;
        mblk = (id - 1024) >> 1; nblk = id & 1; omode = 0;
    }

    f32x4 acc[4][4];
    #pragma unroll
    for (int i = 0; i < 4; ++i)
        #pragma unroll
        for (int j = 0; j < 4; ++j) acc[i][j] = (f32x4){0.f, 0.f, 0.f, 0.f};

    const size_t arow0 = (size_t)mblk * 128;
    const int brow0 = nblk * 128;

    for (int kk = 0; kk < 4; ++kk) {
        const int d0 = kk * 64;
        if (omode == 2) {
            #pragma unroll
            for (int i = 0; i < 8; ++i) {
                const int idx = i * 256 + tid;
                const int r = idx >> 4, c = (idx & 15) * 4;
                const float4 v = *(const float4*)&srcf[(arow0 + r) * D + d0 + c];
                bf16x4 o;
                o[0] = (bf16)v.x; o[1] = (bf16)v.y; o[2] = (bf16)v.z; o[3] = (bf16)v.w;
                *(bf16x4*)&As[r][c] = o;
            }
            #pragma unroll
            for (int i = 0; i < 4; ++i) {
                const int idx = i * 256 + tid;
                const int r = idx >> 3, c = (idx & 7) * 8;
                *(bf16x8*)&Bs[r][c] = *(const bf16x8*)&W[(size_t)(brow0 + r) * D + d0 + c];
            }
        } else {
            #pragma unroll
            for (int i = 0; i < 4; ++i) {
                const int idx = i * 256 + tid;
                const int r = idx >> 3, c = (idx & 7) * 8;
                *(bf16x8*)&As[r][c] = *(const bf16x8*)&A[(arow0 + r) * D + d0 + c];
                *(bf16x8*)&Bs[r][c] = *(const bf16x8*)&W[(size_t)(brow0 + r) * D + d0 + c];
            }
        }
        __syncthreads();
        #pragma unroll
        for (int h2 = 0; h2 < 2; ++h2) {
            const int ko = h2 * 32 + g * 8;
            bf16x8 af[4], bfr[4];
            #pragma unroll
            for (int i = 0; i < 4; ++i)
                af[i] = *(const bf16x8*)&As[wm * 64 + i * 16 + q15][ko];
            #pragma unroll
            for (int j = 0; j < 4; ++j)
                bfr[j] = *(const bf16x8*)&Bs[wn * 64 + j * 16 + q15][ko];
            #pragma unroll
            for (int i = 0; i < 4; ++i)
                #pragma unroll
                for (int j = 0; j < 4; ++j)
                    acc[i][j] = __builtin_amdgcn_mfma_f32_16x16x32_bf16(
                        af[i], bfr[j], acc[i][j], 0, 0, 0);
        }
        __syncthreads();
    }

    if (omode == 0) {
        #pragma unroll
        for (int i = 0; i < 4; ++i)
            #pragma unroll
            for (int j = 0; j < 4; ++j) {
                const int n_g = nblk * 128 + wn * 64 + j * 16 + q15;
                const float b = bias[n_g];
                #pragma unroll
                for (int r = 0; r < 4; ++r) {
                    const size_t m_g = arow0 + wm * 64 + i * 16 + g * 4 + r;
                    out[m_g * D + n_g] = (bf16)((acc[i][j][r] + b) * QSCALE);
                }
            }
    } else if (omode == 1) {
        bf16* Ls = &smem[0][0][0];
        #pragma unroll
        for (int i = 0; i < 4; ++i)
            #pragma unroll
            for (int j = 0; j < 4; ++j) {
                const int n_loc = wn * 64 + j * 16 + q15;     // 0..127
                const int h_loc = n_loc >> 5, d = n_loc & 31;
                const int gp = d >> 3, e = d & 7;
                const float b = bias[nblk * 128 + n_loc];
                #pragma unroll
                for (int r = 0; r < 4; ++r) {
                    const int m_loc = wm * 64 + i * 16 + g * 4 + r;  // 0..127
                    const int c_loc = m_loc >> 6, kl = m_loc & 63;
                    const int t = ((kl >> 5) << 1) | ((kl >> 2) & 1);
                    const int q15p = ((kl >> 3) & 3) * 4 + (kl & 3);
                    Ls[(h_loc * 2 + c_loc) * 2048 + t * 512
                       + (gp * 16 + q15p) * 8 + e] = (bf16)(acc[i][j][r] + b);
                }
            }
        __syncthreads();
        const int bb = (int)(arow0 >> 12);
        const int c0 = (int)((arow0 & 4095) >> 6);
        const int h0 = (nblk * 128) >> 5;
        #pragma unroll
        for (int p = 0; p < 8; ++p) {
            const int idx = p * 2048 + tid * 8;
            const int blk = idx >> 11, within = idx & 2047;
            *(bf16x8*)&out[((size_t)(bb * 8 + h0 + (blk >> 1)) * 64
                            + c0 + (blk & 1)) * 2048 + within]
                = *(const bf16x8*)&Ls[idx];
        }
    } else {
        #pragma unroll
        for (int i = 0; i < 4; ++i)
            #pragma unroll
            for (int j = 0; j < 4; ++j) {
                const int n_g = nblk * 128 + wn * 64 + j * 16 + q15;
                const int h = n_g >> 5, d = n_g & 31;
                const int dt = d >> 4, q15p = d & 15;
                const float b = bias[n_g];
                const size_t m_g0 = arow0 + wm * 64 + i * 16 + g * 4;
                const int bb = (int)(m_g0 >> 12);
                const int c = (int)((m_g0 & 4095) >> 6);
                const int kl0 = (int)(m_g0 & 63);
                const int half = kl0 >> 5, gp = (kl0 >> 3) & 3, e0 = kl0 & 7;
                const int f = dt * 2 + half;
                bf16x4 o;
                #pragma unroll
                for (int r = 0; r < 4; ++r) o[r] = (bf16)(acc[i][j][r] + b);
                *(bf16x4*)&out[((size_t)(bb * 8 + h) * 64 + c) * 2048
                               + f * 512 + (gp * 16 + q15p) * 8 + e0] = o;
            }
    }
}

// ---------------------------------------------------------------------------
// split-KV flash attention, 4 Q-frags per wave, S=16 splits:
// grid = (b*S+split)*8 + h = 1024 blocks = 4 blocks/CU = 16 waves/CU.
// (r13 lesson: 4-frag at 512 blocks lost in occupancy what it won in traffic.)
// All 4 waves of a block read the same K/V chunk (differ only in Q) -> L1.
// l via ones-MFMA (row-sum in every C column) replaces 16 VALU adds/frag.
// ---------------------------------------------------------------------------
template<int S>
__global__ __launch_bounds__(256, 4) void attn_kernel(
    const bf16* __restrict__ Qb, const bf16* __restrict__ Kt,
    const bf16* __restrict__ Vt2,
    bf16* __restrict__ accp, float* __restrict__ lp)
{
    const int tid = threadIdx.x, lane = tid & 63, wid = tid >> 6;
    const int q15 = lane & 15, g = lane >> 4;
    const int bid = blockIdx.x;
    const int h = bid & 7;
    const int inner = bid >> 3;      // b*S + split
    const int split = inner % S;
    const int b = inner / S;
    constexpr int CHUNKS = LS_ / S / 64;

    const int q0 = b * LQ_ + wid * 64;
    bf16x8 qf[4];
    #pragma unroll
    for (int f = 0; f < 4; ++f)
        qf[f] = *(const bf16x8*)&Qb[(size_t)(q0 + f * 16 + q15) * D + h * HD + g * 8];

    const f32x4 minit = (f32x4){-8.f, -8.f, -8.f, -8.f};
    bf16x8 ones;
    #pragma unroll
    for (int e = 0; e < 8; ++e) ones[e] = (bf16)1.0f;

    const size_t cbase = ((size_t)(b * 8 + h) * 64 + split * CHUNKS) * 2048;
    const bf16* kp = Kt + cbase + lane * 8;
    const bf16* vp = Vt2 + cbase + lane * 8;

    f32x4 a0[4], a1[4], al[4];
    #pragma unroll
    for (int f = 0; f < 4; ++f) {
        a0[f] = (f32x4){0.f, 0.f, 0.f, 0.f};
        a1[f] = (f32x4){0.f, 0.f, 0.f, 0.f};
        al[f] = (f32x4){0.f, 0.f, 0.f, 0.f};
    }

    for (int kc = 0; kc < CHUNKS; ++kc) {
        const size_t co = (size_t)kc * 2048;

        bf16x8 kf[4], vf[4];
        #pragma unroll
        for (int t = 0; t < 4; ++t) kf[t] = *(const bf16x8*)&kp[co + t * 512];
        #pragma unroll
        for (int t = 0; t < 4; ++t) vf[t] = *(const bf16x8*)&vp[co + t * 512];

        #pragma unroll
        for (int f = 0; f < 4; ++f) {
            f32x4 s0 = __builtin_amdgcn_mfma_f32_16x16x32_bf16(kf[0], qf[f], minit, 0, 0, 0);
            f32x4 s1 = __builtin_amdgcn_mfma_f32_16x16x32_bf16(kf[1], qf[f], minit, 0, 0, 0);
            f32x4 s2 = __builtin_amdgcn_mfma_f32_16x16x32_bf16(kf[2], qf[f], minit, 0, 0, 0);
            f32x4 s3 = __builtin_amdgcn_mfma_f32_16x16x32_bf16(kf[3], qf[f], minit, 0, 0, 0);

            bf16x8 pa0, pa1;
            #pragma unroll
            for (int r = 0; r < 4; ++r) {
                pa0[r]     = (bf16)exp2f(s0[r]);
                pa0[4 + r] = (bf16)exp2f(s1[r]);
                pa1[r]     = (bf16)exp2f(s2[r]);
                pa1[4 + r] = (bf16)exp2f(s3[r]);
            }

            a0[f] = __builtin_amdgcn_mfma_f32_16x16x32_bf16(pa0, vf[0], a0[f], 0, 0, 0);
            a0[f] = __builtin_amdgcn_mfma_f32_16x16x32_bf16(pa1, vf[1], a0[f], 0, 0, 0);
            a1[f] = __builtin_amdgcn_mfma_f32_16x16x32_bf16(pa0, vf[2], a1[f], 0, 0, 0);
            a1[f] = __builtin_amdgcn_mfma_f32_16x16x32_bf16(pa1, vf[3], a1[f], 0, 0, 0);
            al[f] = __builtin_amdgcn_mfma_f32_16x16x32_bf16(pa0, ones,  al[f], 0, 0, 0);
            al[f] = __builtin_amdgcn_mfma_f32_16x16x32_bf16(pa1, ones,  al[f], 0, 0, 0);
        }
    }

    // al[f][r] = l for q-row (g*4+r) of frag f (identical across q15) ->
    // lanes with q15==0 (g = 0..3) cover q = 0..15.
    const int task0 = (b * 8 + h) * 16 + wid * 4;
    #pragma unroll
    for (int f = 0; f < 4; ++f) {
        const size_t base = ((size_t)((task0 + f) * S + split) * 64 + lane) * 8;
        bf16x4 o0, o1;
        #pragma unroll
        for (int r = 0; r < 4; ++r) {
            o0[r] = (bf16)a0[f][r];
            o1[r] = (bf16)a1[f][r];
        }
        *(bf16x4*)&accp[base]     = o0;
        *(bf16x4*)&accp[base + 4] = o1;
        if (q15 == 0) {
            #pragma unroll
            for (int r = 0; r < 4; ++r)
                lp[((task0 + f) * S + split) * 16 + g * 4 + r] = al[f][r];
        }
    }
}

// ---------------------------------------------------------------------------
// combine split partials (bf16 in, f32 accumulate): 1 wave per task.
// [kept SEPARATE: r12 showed fusing into out_ln costs ~6 us]
// ---------------------------------------------------------------------------
template<int S>
__global__ __launch_bounds__(256) void attn_combine(
    const bf16* __restrict__ accp, const float* __restrict__ lp,
    bf16* __restrict__ Ob)
{
    const int tid = threadIdx.x, lane = tid & 63, wid = tid >> 6;
    const int task = blockIdx.x * 4 + wid;
    const int g = lane >> 4, q15 = lane & 15;

    f32x4 o0 = (f32x4){0.f, 0.f, 0.f, 0.f};
    f32x4 o1 = (f32x4){0.f, 0.f, 0.f, 0.f};
    float ll = 0.f;
    #pragma unroll
    for (int s = 0; s < S; ++s) {
        const size_t base = ((size_t)(task * S + s) * 64 + lane) * 8;
        const bf16x8 v = *(const bf16x8*)&accp[base];
        #pragma unroll
        for (int r = 0; r < 4; ++r) { o0[r] += (float)v[r]; o1[r] += (float)v[4 + r]; }
        if (lane < 16) ll += lp[(task * S + s) * 16 + lane];
    }

    const int b = task >> 7, h = (task >> 4) & 7, qg = task & 15;
    #pragma unroll
    for (int r = 0; r < 4; ++r) {
        const float inv = 1.f / __shfl(ll, g * 4 + r);
        const size_t row = (size_t)b * LQ_ + qg * 16 + g * 4 + r;
        Ob[row * D + h * HD + q15]      = (bf16)(o0[r] * inv);
        Ob[row * D + h * HD + 16 + q15] = (bf16)(o1[r] * inv);
    }
}

// ---------------------------------------------------------------------------
// fused output projection + bias + residual + LayerNorm.  [r10-proven:
// grid 64 x 32-row tiles]
// ---------------------------------------------------------------------------
__global__ __launch_bounds__(256) void out_ln_kernel(
    const bf16* __restrict__ Ob, const bf16* __restrict__ Wout,
    const float* __restrict__ out_b, const float* __restrict__ query,
    const float* __restrict__ lnw, const float* __restrict__ lnb,
    float* __restrict__ out)
{
    __shared__ bf16 As[32][72];
    __shared__ bf16 Bs[256][72];
    __shared__ float red[2][32][2];
    const int tid = threadIdx.x, lane = tid & 63, wid = tid >> 6;
    const int wm = wid >> 1, wn = wid & 1;
    const int g = lane >> 4, q15 = lane & 15;
    const size_t row0 = (size_t)blockIdx.x * 32;

    f32x4 acc[8];
    #pragma unroll
    for (int j = 0; j < 8; ++j) acc[j] = (f32x4){0.f, 0.f, 0.f, 0.f};

    for (int kk = 0; kk < 4; ++kk) {
        const int d0 = kk * 64;
        {   // stage A: 32 x 64, one bf16x8 per thread
            const int r = tid >> 3, c = (tid & 7) * 8;
            *(bf16x8*)&As[r][c] = *(const bf16x8*)&Ob[(row0 + r) * D + d0 + c];
        }
        #pragma unroll
        for (int i = 0; i < 8; ++i) {
            const int idx = i * 256 + tid;
            const int r = idx >> 3, c = (idx & 7) * 8;
            *(bf16x8*)&Bs[r][c] = *(const bf16x8*)&Wout[(size_t)r * D + d0 + c];
        }
        __syncthreads();
        #pragma unroll
        for (int h2 = 0; h2 < 2; ++h2) {
            const int ko = h2 * 32 + g * 8;
            const bf16x8 af = *(const bf16x8*)&As[wm * 16 + q15][ko];
            #pragma unroll
            for (int j = 0; j < 8; ++j) {
                const bf16x8 bfr = *(const bf16x8*)&Bs[wn * 128 + j * 16 + q15][ko];
                acc[j] = __builtin_amdgcn_mfma_f32_16x16x32_bf16(af, bfr, acc[j], 0, 0, 0);
            }
        }
        __syncthreads();
    }

    float bl[8], lw[8], lbv[8];
    #pragma unroll
    for (int j = 0; j < 8; ++j) {
        const int n = wn * 128 + j * 16 + q15;
        bl[j] = out_b[n]; lw[j] = lnw[n]; lbv[j] = lnb[n];
    }

    #pragma unroll
    for (int r = 0; r < 4; ++r) {
        const int rl = wm * 16 + g * 4 + r;
        const size_t m = row0 + rl;
        float s = 0.f, sq = 0.f;
        #pragma unroll
        for (int j = 0; j < 8; ++j) {
            const float v = acc[j][r] + bl[j] + query[m * D + wn * 128 + j * 16 + q15];
            acc[j][r] = v;
            s += v; sq += v * v;
        }
        s += __shfl_xor(s, 1);  sq += __shfl_xor(sq, 1);
        s += __shfl_xor(s, 2);  sq += __shfl_xor(sq, 2);
        s += __shfl_xor(s, 4);  sq += __shfl_xor(sq, 4);
        s += __shfl_xor(s, 8);  sq += __shfl_xor(sq, 8);
        if (q15 == r) {
            red[wn][rl][0] = s;
            red[wn][rl][1] = sq;
        }
    }
    __syncthreads();

    #pragma unroll
    for (int r = 0; r < 4; ++r) {
        const int rl = wm * 16 + g * 4 + r;
        const float s  = red[0][rl][0] + red[1][rl][0];
        const float sq = red[0][rl][1] + red[1][rl][1];
        const float mean = s * (1.f / 256.f);
        const float var  = sq * (1.f / 256.f) - mean * mean;
        const float inv  = rsqrtf(var + 1e-5f);
        const size_t m = row0 + rl;
        #pragma unroll
        for (int j = 0; j < 8; ++j)
            out[m * D + wn * 128 + j * 16 + q15] =
                (acc[j][r] - mean) * inv * lw[j] + lbv[j];
    }
}

// ---------------------------------------------------------------------------
extern "C" void kernel_launch(void* const* d_in, const int* in_sizes, int n_in,
                              void* d_out, int out_size, void* d_ws, size_t ws_size,
                              hipStream_t stream) {
    (void)in_sizes; (void)n_in; (void)out_size; (void)ws_size;
    const float* source    = (const float*)d_in[0];
    const float* query     = (const float*)d_in[1];
    const float* source_pe = (const float*)d_in[2];
    const float* query_pe  = (const float*)d_in[3];
    const float* in_proj_w = (const float*)d_in[4];
    const float* in_proj_b = (const float*)d_in[5];
    const float* out_w     = (const float*)d_in[6];
    const float* out_b     = (const float*)d_in[7];
    const float* ln_w      = (const float*)d_in[8];
    const float* ln_b      = (const float*)d_in[9];

    constexpr int S = 16;
    // workspace layout, ~72 MB (ws is ~268 MB per harness poison)
    bf16* Wb   = (bf16*)d_ws;                  //  0.5 MB
    bf16* QPb  = Wb + 1024 * 256;              //  1 MB
    bf16* Qb   = QPb + (size_t)MQ * D;         //  1 MB
    bf16* Kt   = Qb + (size_t)MQ * D;          // 16.78 MB (K fragment layout)
    bf16* Vt2  = Kt + (size_t)MS * D;          // 16.78 MB (V fragment layout)
    bf16* SPb  = Vt2 + (size_t)MS * D;         // 16.78 MB
    bf16* Ob   = SPb + (size_t)MS * D;         //  1 MB
    bf16* accp = Ob + (size_t)MQ * D;          // 16.78 MB (bf16 partials, S=16)
    float* lp  = (float*)(accp + (size_t)1024 * S * 64 * 8);  // 1 MB
    float* outp = (float*)d_out;

    prep<<<dim3(2048), dim3(256), 0, stream>>>(
        source, source_pe, query, query_pe, in_proj_w, out_w,
        SPb, QPb, Wb);
    gemm_proj<<<dim3(1056), dim3(256), 0, stream>>>(
        SPb, source, QPb, Wb, in_proj_b, Kt, Vt2, Qb);
    attn_kernel<S><<<dim3(NB_ * S * 8), dim3(256), 0, stream>>>(Qb, Kt, Vt2, accp, lp);
    attn_combine<S><<<dim3(256), dim3(256), 0, stream>>>(accp, lp, Ob);
    out_ln_kernel<<<dim3(64), dim3(256), 0, stream>>>(
        Ob, Wb + 768 * 256, out_b, query, ln_w, ln_b, outp);
}

// Round 15
// 80.932 us; speedup vs baseline: 1.0495x; 1.0495x over previous
//
#include <hip/hip_runtime.h>
#include <hip/hip_bf16.h>

typedef __bf16 bf16;
typedef __bf16 bf16x4 __attribute__((ext_vector_type(4)));
typedef __bf16 bf16x8 __attribute__((ext_vector_type(8)));
typedef float f32x4 __attribute__((ext_vector_type(4)));

#define D 256          // embed dim
#define NHEAD 8
#define HD 32          // head dim
#define NB_ 8
#define LQ_ 256
#define LS_ 4096
#define MQ (NB_ * LQ_)   // 2048
#define MS (NB_ * LS_)   // 32768

// softmax scale folded into Q projection: hd^-0.5 * log2(e)
#define QSCALE 0.25500527f

// ---------------------------------------------------------------------------
// prep: SPb = bf16(source+pe); QPb = bf16(query+qpe); Wb = bf16(weights).
// Streams ~90MB at BW; warms L3 with f32 source for the V-GEMM staging.
// [r10-proven best; r11 (deleted) regressed gemm 18 -> 95 us: L3-warmth]
// ---------------------------------------------------------------------------
__global__ __launch_bounds__(256) void prep(
    const float* __restrict__ source, const float* __restrict__ source_pe,
    const float* __restrict__ query, const float* __restrict__ query_pe,
    const float* __restrict__ w_in, const float* __restrict__ w_out,
    bf16* __restrict__ SPb, bf16* __restrict__ QPb, bf16* __restrict__ Wb)
{
    const int NS4 = MS * D / 4;                  // 2097152
    const int NQ4 = MQ * D / 4;                  // 131072
    const int NW4 = (768 * 256 + 256 * 256) / 4; // 65536
    const int total = NS4 + NQ4 + NW4;
    for (int i = blockIdx.x * 256 + threadIdx.x; i < total; i += gridDim.x * 256) {
        if (i < NS4) {
            const float4 s = ((const float4*)source)[i];
            const float4 p = ((const float4*)source_pe)[i];
            bf16x4 osp;
            osp[0] = (bf16)(s.x + p.x); osp[1] = (bf16)(s.y + p.y);
            osp[2] = (bf16)(s.z + p.z); osp[3] = (bf16)(s.w + p.w);
            ((bf16x4*)SPb)[i] = osp;
        } else if (i < NS4 + NQ4) {
            const int j = i - NS4;
            const float4 s = ((const float4*)query)[j];
            const float4 p = ((const float4*)query_pe)[j];
            bf16x4 o;
            o[0] = (bf16)(s.x + p.x); o[1] = (bf16)(s.y + p.y);
            o[2] = (bf16)(s.z + p.z); o[3] = (bf16)(s.w + p.w);
            ((bf16x4*)QPb)[j] = o;
        } else {
            const int j = i - NS4 - NQ4;
            const float4 v = (j < 49152) ? ((const float4*)w_in)[j]
                                         : ((const float4*)w_out)[j - 49152];
            bf16x4 o;
            o[0] = (bf16)v.x; o[1] = (bf16)v.y; o[2] = (bf16)v.z; o[3] = (bf16)v.w;
            ((bf16x4*)Wb)[j] = o;
        }
    }
}

// ---------------------------------------------------------------------------
// projection GEMM, 128x128 tiles, ONE dispatch (grid 1056):  [r10-proven]
//   id<512   : K from SPb (bf16 staging)   -> Kt via LDS restage
//   id<1024  : V from f32 source (L3-warm) -> Vt2 direct (coalesced 8B)
//   id<1056  : Q from QPb                  -> Qb row-major, scaled
// K fragment layout  [bh][c64][t:4][lane:64][e:8]:
//   kl = 32*(t>>1) + 4*(t&1) + 8*(q15'>>2) + (q15'&3),  d = g'*8 + e
// V fragment layout  [bh][c64][f:4][lane:64][e:8]:
//   f = (d>>4)*2 + (kl>>5),  kv = (kl>>5)*32 + g'*8 + e,  d = (f>>1)*16 + q15'
// ---------------------------------------------------------------------------
__global__ __launch_bounds__(256, 4) void gemm_proj(
    const bf16* __restrict__ SPb, const float* __restrict__ srcf,
    const bf16* __restrict__ QPb, const bf16* __restrict__ Wb,
    const float* __restrict__ in_proj_b,
    bf16* __restrict__ Kt, bf16* __restrict__ Vt2, bf16* __restrict__ Qb)
{
    __shared__ __align__(16) bf16 smem[2][128][72];   // As ++ Bs (36KB)
    bf16 (*As)[72] = smem[0];
    bf16 (*Bs)[72] = smem[1];
    const int tid = threadIdx.x, lane = tid & 63, wid = tid >> 6;
    const int wm = wid >> 1, wn = wid & 1;
    const int g = lane >> 4, q15 = lane & 15;
    const int id = blockIdx.x;

    const bf16* A; const bf16* W; const float* bias; bf16* out;
    int omode, mblk, nblk;        // omode: 0=Q row-major, 1=Kt, 2=Vt2
    if (id < 512) {
        A = SPb; W = Wb + 256 * D; bias = in_proj_b + 256; out = Kt;
        mblk = id >> 1; nblk = id & 1; omode = 1;
    } else if (id < 1024) {
        A = nullptr; W = Wb + 512 * D; bias = in_proj_b + 512; out = Vt2;
        mblk = (id - 512) >> 1; nblk = id & 1; omode = 2;
    } else {
        A = QPb; W = Wb; bias = in_proj_b; out = Qb;
        mblk = (id - 1024) >> 1; nblk = id & 1; omode = 0;
    }

    f32x4 acc[4][4];
    #pragma unroll
    for (int i = 0; i < 4; ++i)
        #pragma unroll
        for (int j = 0; j < 4; ++j) acc[i][j] = (f32x4){0.f, 0.f, 0.f, 0.f};

    const size_t arow0 = (size_t)mblk * 128;
    const int brow0 = nblk * 128;

    for (int kk = 0; kk < 4; ++kk) {
        const int d0 = kk * 64;
        if (omode == 2) {
            // stage A from f32 source (+cvt), coalesced float4; L3-warm
            #pragma unroll
            for (int i = 0; i < 8; ++i) {
                const int idx = i * 256 + tid;       // 0..2047 float4 units
                const int r = idx >> 4, c = (idx & 15) * 4;
                const float4 v = *(const float4*)&srcf[(arow0 + r) * D + d0 + c];
                bf16x4 o;
                o[0] = (bf16)v.x; o[1] = (bf16)v.y; o[2] = (bf16)v.z; o[3] = (bf16)v.w;
                *(bf16x4*)&As[r][c] = o;
            }
            #pragma unroll
            for (int i = 0; i < 4; ++i) {
                const int idx = i * 256 + tid;
                const int r = idx >> 3, c = (idx & 7) * 8;
                *(bf16x8*)&Bs[r][c] = *(const bf16x8*)&W[(size_t)(brow0 + r) * D + d0 + c];
            }
        } else {
            #pragma unroll
            for (int i = 0; i < 4; ++i) {
                const int idx = i * 256 + tid;
                const int r = idx >> 3, c = (idx & 7) * 8;
                *(bf16x8*)&As[r][c] = *(const bf16x8*)&A[(arow0 + r) * D + d0 + c];
                *(bf16x8*)&Bs[r][c] = *(const bf16x8*)&W[(size_t)(brow0 + r) * D + d0 + c];
            }
        }
        __syncthreads();
        #pragma unroll
        for (int h2 = 0; h2 < 2; ++h2) {
            const int ko = h2 * 32 + g * 8;
            bf16x8 af[4], bfr[4];
            #pragma unroll
            for (int i = 0; i < 4; ++i)
                af[i] = *(const bf16x8*)&As[wm * 64 + i * 16 + q15][ko];
            #pragma unroll
            for (int j = 0; j < 4; ++j)
                bfr[j] = *(const bf16x8*)&Bs[wn * 64 + j * 16 + q15][ko];
            #pragma unroll
            for (int i = 0; i < 4; ++i)
                #pragma unroll
                for (int j = 0; j < 4; ++j)
                    acc[i][j] = __builtin_amdgcn_mfma_f32_16x16x32_bf16(
                        af[i], bfr[j], acc[i][j], 0, 0, 0);
        }
        __syncthreads();
    }

    if (omode == 0) {
        #pragma unroll
        for (int i = 0; i < 4; ++i)
            #pragma unroll
            for (int j = 0; j < 4; ++j) {
                const int n_g = nblk * 128 + wn * 64 + j * 16 + q15;
                const float b = bias[n_g];
                #pragma unroll
                for (int r = 0; r < 4; ++r) {
                    const size_t m_g = arow0 + wm * 64 + i * 16 + g * 4 + r;
                    out[m_g * D + n_g] = (bf16)((acc[i][j][r] + b) * QSCALE);
                }
            }
    } else if (omode == 1) {
        // K: restage through LDS in Kt destination order, then coalesced copy.
        bf16* Ls = &smem[0][0][0];                 // 32KB needed, 36KB available
        #pragma unroll
        for (int i = 0; i < 4; ++i)
            #pragma unroll
            for (int j = 0; j < 4; ++j) {
                const int n_loc = wn * 64 + j * 16 + q15;     // 0..127
                const int h_loc = n_loc >> 5, d = n_loc & 31;
                const int gp = d >> 3, e = d & 7;
                const float b = bias[nblk * 128 + n_loc];
                #pragma unroll
                for (int r = 0; r < 4; ++r) {
                    const int m_loc = wm * 64 + i * 16 + g * 4 + r;  // 0..127
                    const int c_loc = m_loc >> 6, kl = m_loc & 63;
                    const int t = ((kl >> 5) << 1) | ((kl >> 2) & 1);
                    const int q15p = ((kl >> 3) & 3) * 4 + (kl & 3);
                    Ls[(h_loc * 2 + c_loc) * 2048 + t * 512
                       + (gp * 16 + q15p) * 8 + e] = (bf16)(acc[i][j][r] + b);
                }
            }
        __syncthreads();
        const int bb = (int)(arow0 >> 12);
        const int c0 = (int)((arow0 & 4095) >> 6);
        const int h0 = (nblk * 128) >> 5;
        #pragma unroll
        for (int p = 0; p < 8; ++p) {
            const int idx = p * 2048 + tid * 8;
            const int blk = idx >> 11, within = idx & 2047;
            *(bf16x8*)&out[((size_t)(bb * 8 + h0 + (blk >> 1)) * 64
                            + c0 + (blk & 1)) * 2048 + within]
                = *(const bf16x8*)&Ls[idx];
        }
    } else {
        // V -> Vt2 fragment layout (8B stores, wave-contiguous; proven r6-r10)
        #pragma unroll
        for (int i = 0; i < 4; ++i)
            #pragma unroll
            for (int j = 0; j < 4; ++j) {
                const int n_g = nblk * 128 + wn * 64 + j * 16 + q15;
                const int h = n_g >> 5, d = n_g & 31;
                const int dt = d >> 4, q15p = d & 15;
                const float b = bias[n_g];
                const size_t m_g0 = arow0 + wm * 64 + i * 16 + g * 4;
                const int bb = (int)(m_g0 >> 12);
                const int c = (int)((m_g0 & 4095) >> 6);
                const int kl0 = (int)(m_g0 & 63);
                const int half = kl0 >> 5, gp = (kl0 >> 3) & 3, e0 = kl0 & 7;
                const int f = dt * 2 + half;
                bf16x4 o;
                #pragma unroll
                for (int r = 0; r < 4; ++r) o[r] = (bf16)(acc[i][j][r] + b);
                *(bf16x4*)&out[((size_t)(bb * 8 + h) * 64 + c) * 2048
                               + f * 512 + (gp * 16 + q15p) * 8 + e0] = o;
            }
    }
}

// ---------------------------------------------------------------------------
// split-KV flash attention: LDS-free, barrier-free, coalesced loads,
// 32 q-rows per wave (2 Q-frags share every K/V load).  S=8, grid 1024 =
// 4 blocks/CU = 16 waves/CU.  Partials stored as bf16.  [r10-proven best;
// r13 (4-frag,512blk) and r14 (4-frag,S=16,ones-MFMA) were both washes:
// the kernel sits at its exp2 throughput floor]
// ---------------------------------------------------------------------------
template<int S>
__global__ __launch_bounds__(256, 4) void attn_kernel(
    const bf16* __restrict__ Qb, const bf16* __restrict__ Kt,
    const bf16* __restrict__ Vt2,
    bf16* __restrict__ accp, float* __restrict__ lp)
{
    const int tid = threadIdx.x, lane = tid & 63, wid = tid >> 6;
    const int q15 = lane & 15, g = lane >> 4;
    const int bid = blockIdx.x;
    const int h = bid & 7;
    const int inner = bid >> 3;
    const int split = inner % S;
    const int tmp = inner / S;
    const int qt = tmp & 1;
    const int b = tmp >> 1;
    constexpr int CHUNKS = LS_ / S / 64;

    const int q0 = b * LQ_ + qt * 128 + wid * 32;
    const bf16x8 qfA = *(const bf16x8*)&Qb[(size_t)(q0 + q15) * D + h * HD + g * 8];
    const bf16x8 qfB = *(const bf16x8*)&Qb[(size_t)(q0 + 16 + q15) * D + h * HD + g * 8];

    const f32x4 minit = (f32x4){-8.f, -8.f, -8.f, -8.f};
    const size_t cbase = ((size_t)(b * 8 + h) * 64 + split * CHUNKS) * 2048;
    const bf16* kp = Kt + cbase + lane * 8;
    const bf16* vp = Vt2 + cbase + lane * 8;

    float lA = 0.f, lB = 0.f;
    f32x4 accA0 = (f32x4){0.f, 0.f, 0.f, 0.f};
    f32x4 accA1 = (f32x4){0.f, 0.f, 0.f, 0.f};
    f32x4 accB0 = (f32x4){0.f, 0.f, 0.f, 0.f};
    f32x4 accB1 = (f32x4){0.f, 0.f, 0.f, 0.f};

    for (int kc = 0; kc < CHUNKS; ++kc) {
        const size_t co = (size_t)kc * 2048;

        bf16x8 kf[4], vf[4];
        #pragma unroll
        for (int t = 0; t < 4; ++t) kf[t] = *(const bf16x8*)&kp[co + t * 512];
        #pragma unroll
        for (int f = 0; f < 4; ++f) vf[f] = *(const bf16x8*)&vp[co + f * 512];

        f32x4 sA[4], sB[4];
        #pragma unroll
        for (int t = 0; t < 4; ++t)
            sA[t] = __builtin_amdgcn_mfma_f32_16x16x32_bf16(kf[t], qfA, minit, 0, 0, 0);
        #pragma unroll
        for (int t = 0; t < 4; ++t)
            sB[t] = __builtin_amdgcn_mfma_f32_16x16x32_bf16(kf[t], qfB, minit, 0, 0, 0);

        bf16x8 paA0, paA1, paB0, paB1;
        #pragma unroll
        for (int r = 0; r < 4; ++r) {
            const float a0 = exp2f(sA[0][r]);
            const float a1 = exp2f(sA[1][r]);
            const float a2 = exp2f(sA[2][r]);
            const float a3 = exp2f(sA[3][r]);
            lA += (a0 + a1) + (a2 + a3);
            paA0[r] = (bf16)a0; paA0[4 + r] = (bf16)a1;
            paA1[r] = (bf16)a2; paA1[4 + r] = (bf16)a3;
            const float b0 = exp2f(sB[0][r]);
            const float b1 = exp2f(sB[1][r]);
            const float b2 = exp2f(sB[2][r]);
            const float b3 = exp2f(sB[3][r]);
            lB += (b0 + b1) + (b2 + b3);
            paB0[r] = (bf16)b0; paB0[4 + r] = (bf16)b1;
            paB1[r] = (bf16)b2; paB1[4 + r] = (bf16)b3;
        }

        accA0 = __builtin_amdgcn_mfma_f32_16x16x32_bf16(paA0, vf[0], accA0, 0, 0, 0);
        accA0 = __builtin_amdgcn_mfma_f32_16x16x32_bf16(paA1, vf[1], accA0, 0, 0, 0);
        accA1 = __builtin_amdgcn_mfma_f32_16x16x32_bf16(paA0, vf[2], accA1, 0, 0, 0);
        accA1 = __builtin_amdgcn_mfma_f32_16x16x32_bf16(paA1, vf[3], accA1, 0, 0, 0);
        accB0 = __builtin_amdgcn_mfma_f32_16x16x32_bf16(paB0, vf[0], accB0, 0, 0, 0);
        accB0 = __builtin_amdgcn_mfma_f32_16x16x32_bf16(paB1, vf[1], accB0, 0, 0, 0);
        accB1 = __builtin_amdgcn_mfma_f32_16x16x32_bf16(paB0, vf[2], accB1, 0, 0, 0);
        accB1 = __builtin_amdgcn_mfma_f32_16x16x32_bf16(paB1, vf[3], accB1, 0, 0, 0);
    }

    lA += __shfl_xor(lA, 16);
    lA += __shfl_xor(lA, 32);
    lB += __shfl_xor(lB, 16);
    lB += __shfl_xor(lB, 32);

    const int qg16 = qt * 8 + wid * 2;
    const int taskA = (b * 8 + h) * 16 + qg16;
    const size_t baseA = ((size_t)(taskA * S + split) * 64 + lane) * 8;
    const size_t baseB = ((size_t)((taskA + 1) * S + split) * 64 + lane) * 8;
    bf16x4 oA0, oA1, oB0, oB1;
    #pragma unroll
    for (int r = 0; r < 4; ++r) {
        oA0[r] = (bf16)accA0[r]; oA1[r] = (bf16)accA1[r];
        oB0[r] = (bf16)accB0[r]; oB1[r] = (bf16)accB1[r];
    }
    *(bf16x4*)&accp[baseA]     = oA0;
    *(bf16x4*)&accp[baseA + 4] = oA1;
    *(bf16x4*)&accp[baseB]     = oB0;
    *(bf16x4*)&accp[baseB + 4] = oB1;
    if (lane < 16) {
        lp[(taskA * S + split) * 16 + lane] = lA;
        lp[((taskA + 1) * S + split) * 16 + lane] = lB;
    }
}

// ---------------------------------------------------------------------------
// combine split partials (bf16 in, f32 accumulate): 1 wave per task.
// [kept SEPARATE: r12 proved fusing into out_ln costs ~6 us]
// ---------------------------------------------------------------------------
template<int S>
__global__ __launch_bounds__(256) void attn_combine(
    const bf16* __restrict__ accp, const float* __restrict__ lp,
    bf16* __restrict__ Ob)
{
    const int tid = threadIdx.x, lane = tid & 63, wid = tid >> 6;
    const int task = blockIdx.x * 4 + wid;
    const int g = lane >> 4, q15 = lane & 15;

    f32x4 o0 = (f32x4){0.f, 0.f, 0.f, 0.f};
    f32x4 o1 = (f32x4){0.f, 0.f, 0.f, 0.f};
    float ll = 0.f;
    #pragma unroll
    for (int s = 0; s < S; ++s) {
        const size_t base = ((size_t)(task * S + s) * 64 + lane) * 8;
        const bf16x8 v = *(const bf16x8*)&accp[base];
        #pragma unroll
        for (int r = 0; r < 4; ++r) { o0[r] += (float)v[r]; o1[r] += (float)v[4 + r]; }
        if (lane < 16) ll += lp[(task * S + s) * 16 + lane];
    }

    const int b = task >> 7, h = (task >> 4) & 7, qg = task & 15;
    #pragma unroll
    for (int r = 0; r < 4; ++r) {
        const float inv = 1.f / __shfl(ll, g * 4 + r);
        const size_t row = (size_t)b * LQ_ + qg * 16 + g * 4 + r;
        Ob[row * D + h * HD + q15]      = (bf16)(o0[r] * inv);
        Ob[row * D + h * HD + 16 + q15] = (bf16)(o1[r] * inv);
    }
}

// ---------------------------------------------------------------------------
// fused output projection + bias + residual + LayerNorm.  [r10-proven:
// grid 64 x 32-row tiles for the latency-bound tail]
// ---------------------------------------------------------------------------
__global__ __launch_bounds__(256) void out_ln_kernel(
    const bf16* __restrict__ Ob, const bf16* __restrict__ Wout,
    const float* __restrict__ out_b, const float* __restrict__ query,
    const float* __restrict__ lnw, const float* __restrict__ lnb,
    float* __restrict__ out)
{
    __shared__ bf16 As[32][72];
    __shared__ bf16 Bs[256][72];
    __shared__ float red[2][32][2];
    const int tid = threadIdx.x, lane = tid & 63, wid = tid >> 6;
    const int wm = wid >> 1, wn = wid & 1;
    const int g = lane >> 4, q15 = lane & 15;
    const size_t row0 = (size_t)blockIdx.x * 32;

    f32x4 acc[8];
    #pragma unroll
    for (int j = 0; j < 8; ++j) acc[j] = (f32x4){0.f, 0.f, 0.f, 0.f};

    for (int kk = 0; kk < 4; ++kk) {
        const int d0 = kk * 64;
        {   // stage A: 32 x 64, one bf16x8 per thread
            const int r = tid >> 3, c = (tid & 7) * 8;
            *(bf16x8*)&As[r][c] = *(const bf16x8*)&Ob[(row0 + r) * D + d0 + c];
        }
        #pragma unroll
        for (int i = 0; i < 8; ++i) {
            const int idx = i * 256 + tid;
            const int r = idx >> 3, c = (idx & 7) * 8;
            *(bf16x8*)&Bs[r][c] = *(const bf16x8*)&Wout[(size_t)r * D + d0 + c];
        }
        __syncthreads();
        #pragma unroll
        for (int h2 = 0; h2 < 2; ++h2) {
            const int ko = h2 * 32 + g * 8;
            const bf16x8 af = *(const bf16x8*)&As[wm * 16 + q15][ko];
            #pragma unroll
            for (int j = 0; j < 8; ++j) {
                const bf16x8 bfr = *(const bf16x8*)&Bs[wn * 128 + j * 16 + q15][ko];
                acc[j] = __builtin_amdgcn_mfma_f32_16x16x32_bf16(af, bfr, acc[j], 0, 0, 0);
            }
        }
        __syncthreads();
    }

    float bl[8], lw[8], lbv[8];
    #pragma unroll
    for (int j = 0; j < 8; ++j) {
        const int n = wn * 128 + j * 16 + q15;
        bl[j] = out_b[n]; lw[j] = lnw[n]; lbv[j] = lnb[n];
    }

    #pragma unroll
    for (int r = 0; r < 4; ++r) {
        const int rl = wm * 16 + g * 4 + r;
        const size_t m = row0 + rl;
        float s = 0.f, sq = 0.f;
        #pragma unroll
        for (int j = 0; j < 8; ++j) {
            const float v = acc[j][r] + bl[j] + query[m * D + wn * 128 + j * 16 + q15];
            acc[j][r] = v;
            s += v; sq += v * v;
        }
        s += __shfl_xor(s, 1);  sq += __shfl_xor(sq, 1);
        s += __shfl_xor(s, 2);  sq += __shfl_xor(sq, 2);
        s += __shfl_xor(s, 4);  sq += __shfl_xor(sq, 4);
        s += __shfl_xor(s, 8);  sq += __shfl_xor(sq, 8);
        if (q15 == r) {
            red[wn][rl][0] = s;
            red[wn][rl][1] = sq;
        }
    }
    __syncthreads();

    #pragma unroll
    for (int r = 0; r < 4; ++r) {
        const int rl = wm * 16 + g * 4 + r;
        const float s  = red[0][rl][0] + red[1][rl][0];
        const float sq = red[0][rl][1] + red[1][rl][1];
        const float mean = s * (1.f / 256.f);
        const float var  = sq * (1.f / 256.f) - mean * mean;
        const float inv  = rsqrtf(var + 1e-5f);
        const size_t m = row0 + rl;
        #pragma unroll
        for (int j = 0; j < 8; ++j)
            out[m * D + wn * 128 + j * 16 + q15] =
                (acc[j][r] - mean) * inv * lw[j] + lbv[j];
    }
}

// ---------------------------------------------------------------------------
extern "C" void kernel_launch(void* const* d_in, const int* in_sizes, int n_in,
                              void* d_out, int out_size, void* d_ws, size_t ws_size,
                              hipStream_t stream) {
    (void)in_sizes; (void)n_in; (void)out_size; (void)ws_size;
    const float* source    = (const float*)d_in[0];
    const float* query     = (const float*)d_in[1];
    const float* source_pe = (const float*)d_in[2];
    const float* query_pe  = (const float*)d_in[3];
    const float* in_proj_w = (const float*)d_in[4];
    const float* in_proj_b = (const float*)d_in[5];
    const float* out_w     = (const float*)d_in[6];
    const float* out_b     = (const float*)d_in[7];
    const float* ln_w      = (const float*)d_in[8];
    const float* ln_b      = (const float*)d_in[9];

    constexpr int S = 8;
    // workspace layout, ~63 MB (ws is ~268 MB per harness poison)
    bf16* Wb   = (bf16*)d_ws;                  //  0.5 MB
    bf16* QPb  = Wb + 1024 * 256;              //  1 MB
    bf16* Qb   = QPb + (size_t)MQ * D;         //  1 MB
    bf16* Kt   = Qb + (size_t)MQ * D;          // 16.78 MB (K fragment layout)
    bf16* Vt2  = Kt + (size_t)MS * D;          // 16.78 MB (V fragment layout)
    bf16* SPb  = Vt2 + (size_t)MS * D;         // 16.78 MB
    bf16* Ob   = SPb + (size_t)MS * D;         //  1 MB
    bf16* accp = Ob + (size_t)MQ * D;          //  8.39 MB (bf16 partials)
    float* lp  = (float*)(accp + (size_t)1024 * S * 64 * 8);  // 0.5 MB
    float* outp = (float*)d_out;

    prep<<<dim3(2048), dim3(256), 0, stream>>>(
        source, source_pe, query, query_pe, in_proj_w, out_w,
        SPb, QPb, Wb);
    gemm_proj<<<dim3(1056), dim3(256), 0, stream>>>(
        SPb, source, QPb, Wb, in_proj_b, Kt, Vt2, Qb);
    attn_kernel<S><<<dim3(1024), dim3(256), 0, stream>>>(Qb, Kt, Vt2, accp, lp);
    attn_combine<S><<<dim3(256), dim3(256), 0, stream>>>(accp, lp, Ob);
    out_ln_kernel<<<dim3(64), dim3(256), 0, stream>>>(
        Ob, Wb + 768 * 256, out_b, query, ln_w, ln_b, outp);
}